// Round 8
// baseline (247.599 us; speedup 1.0000x reference)
//
#include <hip/hip_runtime.h>

#define BB 512
#define SS 512
#define TT 78
#define TP 80      // padded tag count (multiple of 4)
#define NT 128     // 2 waves: wave0 = score chain, wave1 = alpha chain

typedef float v2f __attribute__((ext_vector_type(2)));
typedef float v4f __attribute__((ext_vector_type(4)));

__device__ __forceinline__ float fexp(float x) { return __expf(x); }
__device__ __forceinline__ float flog(float x) { return __logf(x); }

// Source-level static loop: body sees the index as a TEMPLATE CONSTANT.
template<int I> struct ic { static constexpr int v = I; };
template<int I, int N, typename F>
__device__ __forceinline__ void sfor(F f) {
    if constexpr (I < N) {
        f(ic<I>{});
        sfor<I + 1, N>(f);
    }
}

__global__ __attribute__((amdgpu_flat_work_group_size(NT, NT),
                          amdgpu_waves_per_eu(1, 1)))
void crf_fwd_kernel(
    const float* __restrict__ em,          // [B,S,T]
    const unsigned int* __restrict__ mi32, // [B,S] int32 OR packed bool bytes
    const float* __restrict__ st,          // [T]
    const float* __restrict__ en_,         // [T]
    const float* __restrict__ tr,          // [T,T] row j (src), col t (dst)
    float* __restrict__ out)               // [B]
{
    const int b    = blockIdx.x;
    const int tid  = threadIdx.x;
    const int wid  = tid >> 6;            // 0 = score (masked), 1 = alpha
    const int lane = tid & 63;
    const bool has2 = lane < (TT - 64);   // lanes 0..13 own a second tag
    const int t0  = lane;                 // always < 78
    const int t1  = lane + 64;
    const int t1c = has2 ? t1 : (TT - 1); // clamped index for safe loads

    __shared__ __align__(16) float sE[2][TP];  // per-wave exp-state vector
    __shared__ float sfin[2];
    __shared__ int sflag;

    // ---- one-time mask layout detection (int32 elements vs 1-byte bools) ----
    if (tid == 0) sflag = 1;
    __syncthreads();
    {
        bool okl = true;
        for (int k = tid; k < 512; k += NT) okl = okl && (mi32[k] <= 1u);
        if (!okl) atomicAnd(&sflag, 0);
    }
    __syncthreads();
    const bool mask_int = (sflag != 0);
    const unsigned char* mi8 = (const unsigned char*)mi32;
    const bool is_alpha = (wid == 1);

    // ---- preload exp(trans[j][t]) columns for my two tags into REGISTERS ----
    // ANTI-REMATERIALIZATION FENCE: rounds 2-6 showed VGPR_Count pinned at 132
    // under every allocation hint — the compiler sinks the loop-invariant
    // exp(tr) loads into the K-loop and recomputes them each step (160
    // quarter-rate v_exp/step ~= the whole measured step time). Values that
    // pass through scalar "+v" asm operands cannot be recomputed, so et must
    // stay register-resident across the loop.
    v2f et0[TP / 2];   // et0[p] = {exp(tr[2p][t0]),  exp(tr[2p+1][t0])}
    v2f et1[TP / 2];   // et1[p] = {exp(tr[2p][t1c]), exp(tr[2p+1][t1c])}
    sfor<0, TP / 2>([&](auto P) {
        constexpr int p  = decltype(P)::v;
        constexpr int j0 = 2 * p, j1 = 2 * p + 1;
        float a0v = (j0 < TT) ? fexp(tr[j0 * TT + t0])  : 0.0f;
        float a1v = (j1 < TT) ? fexp(tr[j1 * TT + t0])  : 0.0f;
        float b0v = (j0 < TT) ? fexp(tr[j0 * TT + t1c]) : 0.0f;
        float b1v = (j1 < TT) ? fexp(tr[j1 * TT + t1c]) : 0.0f;
        asm volatile("" : "+v"(a0v), "+v"(a1v), "+v"(b0v), "+v"(b1v));
        et0[p] = (v2f){a0v, a1v};
        et1[p] = (v2f){b0v, b1v};
    });

    // ---- init state: start + emissions[:,0] ----
    const size_t base = (size_t)b * SS * TT;
    float sc0 = st[t0] + em[base + t0];
    float sc1 = st[t1c] + em[base + t1c];   // junk for !has2, never used

    // zero the LDS padding entries (written once, never overwritten)
    if (lane == 14 || lane == 15) sE[wid][64 + lane] = 0.f;  // slots 78, 79

    // ---- prefetch step 1 ----
    const float* rp = em + base + TT;
    float en0 = rp[t0];
    float en1 = rp[t1c];
    unsigned int mk_n = mask_int ? mi32[b * SS + 1] : (unsigned int)mi8[b * SS + 1];

    for (int i = 1; i < SS; ++i) {
        // broadcast m = state[0] (lane 0's t0 value) via SALU
        float m = __builtin_amdgcn_readfirstlane(sc0);
        sE[wid][lane] = fexp(sc0 - m);
        if (has2) sE[wid][64 + lane] = fexp(sc1 - m);

        const float emi0 = en0, emi1 = en1;
        const unsigned int mki = mk_n;
        if (i + 1 < SS) {                   // prefetch next step
            rp += TT;
            en0 = rp[t0];
            en1 = rp[t1c];
            mk_n = mask_int ? mi32[b * SS + i + 1] : (unsigned int)mi8[b * SS + i + 1];
        }
        __builtin_amdgcn_wave_barrier();    // keep reads after writes (no HW cost)

        // ---- load the ENTIRE exp-state vector into registers first ----
        const v4f* ep = (const v4f*)sE[wid];
        v4f xs[TP / 4];
        sfor<0, TP / 4>([&](auto K) {
            constexpr int k = decltype(K)::v;
            xs[k] = ep[k];
        });

        // matvec: v[t] = sum_j E[j] * exp(trans[j][t]); packed fp32 FMAs
        v2f a0 = {0.f, 0.f}, a1 = {0.f, 0.f};   // accumulators for t0
        v2f c0 = {0.f, 0.f}, c1 = {0.f, 0.f};   // accumulators for t1
        sfor<0, TP / 4>([&](auto K) {           // 20 steps, 4 pk-FMA each
            constexpr int k = decltype(K)::v;
            v2f xlo = {xs[k].x, xs[k].y};
            v2f xhi = {xs[k].z, xs[k].w};
            a0 = __builtin_elementwise_fma(xlo, et0[2 * k + 0], a0);
            a1 = __builtin_elementwise_fma(xhi, et0[2 * k + 1], a1);
            c0 = __builtin_elementwise_fma(xlo, et1[2 * k + 0], c0);
            c1 = __builtin_elementwise_fma(xhi, et1[2 * k + 1], c1);
        });
        v2f va = a0 + a1;
        v2f vc = c0 + c1;
        float v0 = va.x + va.y;
        float v1 = vc.x + vc.y;

        float nsc0 = emi0 + m + flog(v0);
        float nsc1 = emi1 + m + flog(v1);
        const bool upd = is_alpha | (mki != 0);   // alpha always updates
        sc0 = upd ? nsc0 : sc0;
        sc1 = upd ? nsc1 : sc1;
    }

    // ---- final: lse over tags with end transitions (in-wave reduce) ----
    float f0 = sc0 + en_[t0];
    float f1 = has2 ? (sc1 + en_[t1c]) : -1e30f;
    float mm = fmaxf(f0, f1);
    #pragma unroll
    for (int o = 32; o > 0; o >>= 1) mm = fmaxf(mm, __shfl_xor(mm, o));
    float s = fexp(f0 - mm) + (has2 ? fexp(f1 - mm) : 0.f);
    #pragma unroll
    for (int o = 32; o > 0; o >>= 1) s += __shfl_xor(s, o);
    if (lane == 0) sfin[wid] = mm + flog(s);
    __syncthreads();
    if (tid == 0) out[b] = sfin[1] - sfin[0];   // partition - score_final
}

extern "C" void kernel_launch(void* const* d_in, const int* in_sizes, int n_in,
                              void* d_out, int out_size, void* d_ws, size_t ws_size,
                              hipStream_t stream) {
    const float* emissions    = (const float*)d_in[0];
    const unsigned int* mask  = (const unsigned int*)d_in[1];
    const float* start_trans  = (const float*)d_in[2];
    const float* end_trans    = (const float*)d_in[3];
    const float* transitions  = (const float*)d_in[4];
    float* out = (float*)d_out;

    crf_fwd_kernel<<<BB, NT, 0, stream>>>(emissions, mask, start_trans,
                                          end_trans, transitions, out);
}

// Round 9
// 201.083 us; speedup vs baseline: 1.2313x; 1.2313x over previous
//
#include <hip/hip_runtime.h>

#define BB 256     // blocks (2 batches each)
#define SS 512
#define TT 78
#define TP 80      // padded tag count
#define NT 256     // 4 waves: w = 2*batch_local + chain (0=score,1=alpha)

typedef float v2f __attribute__((ext_vector_type(2)));
typedef float v4f __attribute__((ext_vector_type(4)));

template<int I> struct ic { static constexpr int v = I; };
template<int I, int N, typename F>
__device__ __forceinline__ void sfor(F f) {
    if constexpr (I < N) { f(ic<I>{}); sfor<I + 1, N>(f); }
}

__global__ __attribute__((amdgpu_flat_work_group_size(NT, NT)))
void crf_fwd_kernel(const float* __restrict__ em,          // [B,S,T]
                    const unsigned int* __restrict__ mi32, // [B,S]
                    const float* __restrict__ st,
                    const float* __restrict__ en_,
                    const float* __restrict__ tr,          // [T,T]
                    float* __restrict__ out)               // [B]
{
    __shared__ __align__(16) float sE[4][TP];   // per-wave E vector
    __shared__ float sfin[4];
    __shared__ int sflag;
    // OCCUPANCY FORCER: >80KB static LDS -> 1 WG/CU -> RA occupancy target 1
    // -> full 512-VGPR budget. Rounds 2-8: every other lever (SROA, waves_per_eu,
    // asm fence) left the allocator pinned at 132 VGPR (= 512/4-wave target),
    // spilling W to scratch. Grid restructured to 256 blocks x 4 waves so
    // 1 WG/CU still keeps all 1024 chains concurrent.
    __shared__ char lds_pad[84 * 1024];

    const int tid  = threadIdx.x;
    const int w    = tid >> 6;
    const int lane = tid & 63;
    ((volatile char*)lds_pad)[tid] = 0;   // keep pad allocated

    const int  batch    = blockIdx.x * 2 + (w >> 1);
    const bool is_alpha = (w & 1) != 0;
    const bool has2     = lane < (TT - 64);
    const int  t0  = lane;
    const int  t1c = has2 ? (lane + 64) : (TT - 1);

    // ---- mask layout detection (int32 vs byte bools) ----
    if (tid == 0) sflag = 1;
    __syncthreads();
    { bool ok = true;
      for (int k = tid; k < 512; k += NT) ok = ok && (mi32[k] <= 1u);
      if (!ok) atomicAnd(&sflag, 0); }
    __syncthreads();
    const bool mask_int = (sflag != 0);
    const unsigned char* mi8 = (const unsigned char*)mi32;

    // ---- W = exp(trans) columns for my two tags -> registers ----
    v2f et0[TP / 2], et1[TP / 2];
    sfor<0, TP / 2>([&](auto P) {
        constexpr int p = decltype(P)::v;
        constexpr int j0 = 2 * p, j1 = 2 * p + 1;
        float a0v = (j0 < TT) ? __expf(tr[j0 * TT + t0])  : 0.f;
        float a1v = (j1 < TT) ? __expf(tr[j1 * TT + t0])  : 0.f;
        float b0v = (j0 < TT) ? __expf(tr[j0 * TT + t1c]) : 0.f;
        float b1v = (j1 < TT) ? __expf(tr[j1 * TT + t1c]) : 0.f;
        asm volatile("" : "+v"(a0v), "+v"(a1v), "+v"(b0v), "+v"(b1v));
        et0[p] = (v2f){a0v, a1v};
        et1[p] = (v2f){b0v, b1v};
    });

    // ---- linear-domain state: E = exp(state - M2*ln2), M2 integer scale ----
    const size_t base = (size_t)batch * SS * TT;
    float e0 = __expf(st[t0]  + em[base + t0]);
    float e1 = __expf(st[t1c] + em[base + t1c]);
    int M2 = 0;

    if (lane == 14 || lane == 15) sE[w][64 + lane] = 0.f;  // pad slots 78,79
    sE[w][lane] = e0;
    if (has2) sE[w][64 + lane] = e1;

    // prefetch step 1 (exp computed here = off the critical path)
    const float* rp = em + base + TT;
    float EmN0 = __expf(rp[t0]);
    float EmN1 = __expf(rp[t1c]);
    unsigned int mk_n = mask_int ? mi32[batch * SS + 1]
                                 : (unsigned int)mi8[batch * SS + 1];

    for (int i = 1; i < SS; ++i) {
        const float Em0 = EmN0, Em1 = EmN1;
        const unsigned int mki = mk_n;
        if (i + 1 < SS) {
            rp += TT;
            EmN0 = __expf(rp[t0]);
            EmN1 = __expf(rp[t1c]);
            mk_n = mask_int ? mi32[batch * SS + i + 1]
                            : (unsigned int)mi8[batch * SS + i + 1];
        }
        __builtin_amdgcn_wave_barrier();

        // load E vector into registers
        const v4f* ep = (const v4f*)sE[w];
        v4f xs[TP / 4];
        sfor<0, TP / 4>([&](auto K) { constexpr int k = decltype(K)::v; xs[k] = ep[k]; });

        // v[t] = sum_j E[j] * W[j][t]  (pure pk-FMA, no transcendentals)
        v2f a0{0,0}, a1{0,0}, c0{0,0}, c1{0,0};
        sfor<0, TP / 4>([&](auto K) {
            constexpr int k = decltype(K)::v;
            v2f xlo = {xs[k].x, xs[k].y}, xhi = {xs[k].z, xs[k].w};
            a0 = __builtin_elementwise_fma(xlo, et0[2 * k],     a0);
            a1 = __builtin_elementwise_fma(xhi, et0[2 * k + 1], a1);
            c0 = __builtin_elementwise_fma(xlo, et1[2 * k],     c0);
            c1 = __builtin_elementwise_fma(xhi, et1[2 * k + 1], c1);
        });
        v2f va = a0 + a1, vc = c0 + c1;
        float v0 = va.x + va.y;   // v at tag t0
        float v1 = vc.x + vc.y;   // v at tag t1

        // exact power-of-2 renormalization by exponent of lane0's v0
        float vref = __builtin_amdgcn_readfirstlane(v0);
        int   d2   = (int)((__float_as_uint(vref) >> 23) & 0xFF) - 127;
        float scl  = __uint_as_float((unsigned)(127 - d2) << 23);
        float n0 = v0 * scl * Em0;
        float n1 = v1 * scl * Em1;

        const bool upd = is_alpha | (mki != 0);
        e0 = upd ? n0 : e0;
        e1 = upd ? n1 : e1;
        M2 = upd ? M2 + d2 : M2;

        __builtin_amdgcn_wave_barrier();
        sE[w][lane] = e0;
        if (has2) sE[w][64 + lane] = e1;
    }

    // ---- final: ln(sum_t E[t]*exp(end[t])) + M2*ln2 per chain ----
    float fs = e0 * __expf(en_[t0]);
    if (has2) fs += e1 * __expf(en_[t1c]);
    #pragma unroll
    for (int o = 32; o > 0; o >>= 1) fs += __shfl_xor(fs, o);
    if (lane == 0) sfin[w] = __logf(fs) + (float)M2 * 0.6931471805599453f;
    __syncthreads();
    if (tid == 0) {
        out[blockIdx.x * 2 + 0] = sfin[1] - sfin[0];   // partition - score
        out[blockIdx.x * 2 + 1] = sfin[3] - sfin[2];
    }
}

extern "C" void kernel_launch(void* const* d_in, const int* in_sizes, int n_in,
                              void* d_out, int out_size, void* d_ws, size_t ws_size,
                              hipStream_t stream) {
    const float* emissions    = (const float*)d_in[0];
    const unsigned int* mask  = (const unsigned int*)d_in[1];
    const float* start_trans  = (const float*)d_in[2];
    const float* end_trans    = (const float*)d_in[3];
    const float* transitions  = (const float*)d_in[4];
    float* out = (float*)d_out;

    crf_fwd_kernel<<<BB, NT, 0, stream>>>(emissions, mask, start_trans,
                                          end_trans, transitions, out);
}